// Round 1
// baseline (97.432 us; speedup 1.0000x reference)
//
#include <hip/hip_runtime.h>
#include <hip/hip_bf16.h>

#define N_ROWS 8192
#define DIMS   128

typedef __bf16 bf16x8 __attribute__((ext_vector_type(8)));
typedef float  f32x4  __attribute__((ext_vector_type(4)));

// ---------------------------------------------------------------------------
// init: minrow = +inf, zero the accumulator block (colsum1, colsum2,
// colsumsq1, colsumsq2-dummy = 512 floats)
// ---------------------------------------------------------------------------
__global__ __launch_bounds__(256) void init_k(unsigned* __restrict__ minrow,
                                              float* __restrict__ accum) {
    int i = blockIdx.x * 256 + threadIdx.x;
    if (i < N_ROWS) minrow[i] = 0x7F800000u;   // +inf bits
    if (i < 512)    accum[i]  = 0.0f;
}

// ---------------------------------------------------------------------------
// prep: fp32 [8192,128] -> bf16 copy (scaled), exact row sq-norms,
// column sums + column sums of squares (fp32, atomics per block).
// One wave per row iteration: lane handles cols lane and lane+64.
// ---------------------------------------------------------------------------
__global__ __launch_bounds__(256) void prep_k(const float* __restrict__ src,
                                              __hip_bfloat16* __restrict__ dstb,
                                              float* __restrict__ sq,
                                              float* __restrict__ colsum,
                                              float* __restrict__ colsumsq,
                                              float scale) {
    const int lane = threadIdx.x & 63;
    const int wave = threadIdx.x >> 6;
    const int gw   = blockIdx.x * 4 + wave;
    const int nw   = gridDim.x * 4;

    float cs0 = 0.f, cs1 = 0.f, cq0 = 0.f, cq1 = 0.f;

    for (int row = gw; row < N_ROWS; row += nw) {
        float x0 = src[row * DIMS + lane];
        float x1 = src[row * DIMS + 64 + lane];
        dstb[row * DIMS + lane]      = __float2bfloat16(scale * x0);
        dstb[row * DIMS + 64 + lane] = __float2bfloat16(scale * x1);
        float s = x0 * x0 + x1 * x1;
        #pragma unroll
        for (int m = 32; m; m >>= 1) s += __shfl_xor(s, m);
        if (lane == 0) sq[row] = s;
        cs0 += x0; cs1 += x1;
        cq0 += x0 * x0; cq1 += x1 * x1;
    }

    __shared__ float lds[4][DIMS];
    lds[wave][lane]      = cs0;
    lds[wave][64 + lane] = cs1;
    __syncthreads();
    if (threadIdx.x < DIMS) {
        float t = lds[0][threadIdx.x] + lds[1][threadIdx.x] +
                  lds[2][threadIdx.x] + lds[3][threadIdx.x];
        atomicAdd(&colsum[threadIdx.x], t);
    }
    __syncthreads();
    lds[wave][lane]      = cq0;
    lds[wave][64 + lane] = cq1;
    __syncthreads();
    if (threadIdx.x < DIMS) {
        float t = lds[0][threadIdx.x] + lds[1][threadIdx.x] +
                  lds[2][threadIdx.x] + lds[3][threadIdx.x];
        atomicAdd(&colsumsq[threadIdx.x], t);
    }
}

// ---------------------------------------------------------------------------
// dist: per block 256 rows x 256-col chunk. Wave owns 64 rows (A frags in
// registers, c1b pre-scaled by -2). B frags read from global (L2-resident).
// d2 = acc + sq1 + sq2 ; running min ; shfl-min ; atomicMin per row.
// MFMA: 16x16x32 bf16. A: row = lane&15, k = (lane>>4)*8 + j.
//       B: col = lane&15, k = (lane>>4)*8 + j (B[k][n] = c2[n][k]).
//       D: col = lane&15, row = (lane>>4)*4 + r   [measured m89/m91]
// ---------------------------------------------------------------------------
__global__ __launch_bounds__(256) void dist_k(const __hip_bfloat16* __restrict__ c1b,
                                              const __hip_bfloat16* __restrict__ c2b,
                                              const float* __restrict__ sq1,
                                              const float* __restrict__ sq2,
                                              unsigned* __restrict__ minrow) {
    const int lane = threadIdx.x & 63;
    const int wave = threadIdx.x >> 6;
    const int lo = lane & 15;
    const int hi = lane >> 4;
    const int rb = blockIdx.x >> 5;     // 0..31 row block (256 rows)
    const int cb = blockIdx.x & 31;     // 0..31 col chunk (256 cols)
    const int row0 = rb * 256 + wave * 64;
    const int col0 = cb * 256;

    // A fragments: 4 row-subtiles x 4 k-steps, held in registers.
    bf16x8 a[4][4];
    #pragma unroll
    for (int rt = 0; rt < 4; ++rt)
        #pragma unroll
        for (int ks = 0; ks < 4; ++ks)
            a[rt][ks] = *reinterpret_cast<const bf16x8*>(
                c1b + (size_t)(row0 + rt * 16 + lo) * DIMS + ks * 32 + hi * 8);

    // sq1 for this lane's OUTPUT rows: row = row0 + rt*16 + hi*4 + r
    float s1[4][4];
    #pragma unroll
    for (int rt = 0; rt < 4; ++rt)
        #pragma unroll
        for (int r = 0; r < 4; ++r)
            s1[rt][r] = sq1[row0 + rt * 16 + hi * 4 + r];

    float rmin[4][4];
    #pragma unroll
    for (int rt = 0; rt < 4; ++rt)
        #pragma unroll
        for (int r = 0; r < 4; ++r)
            rmin[rt][r] = __builtin_inff();

    for (int ct = 0; ct < 16; ++ct) {
        const int J = col0 + ct * 16 + lo;
        bf16x8 b[4];
        #pragma unroll
        for (int ks = 0; ks < 4; ++ks)
            b[ks] = *reinterpret_cast<const bf16x8*>(
                c2b + (size_t)J * DIMS + ks * 32 + hi * 8);
        const float t = sq2[J];

        #pragma unroll
        for (int rt = 0; rt < 4; ++rt) {
            f32x4 acc = {0.f, 0.f, 0.f, 0.f};
            #pragma unroll
            for (int ks = 0; ks < 4; ++ks)
                acc = __builtin_amdgcn_mfma_f32_16x16x32_bf16(a[rt][ks], b[ks], acc, 0, 0, 0);
            #pragma unroll
            for (int r = 0; r < 4; ++r) {
                float d2 = acc[r] + s1[rt][r] + t;   // acc = -2 * c1.c2
                rmin[rt][r] = fminf(rmin[rt][r], d2);
            }
        }
    }

    // min across the 16 lanes sharing a row (xor masks 1,2,4,8 stay in group)
    #pragma unroll
    for (int rt = 0; rt < 4; ++rt)
        #pragma unroll
        for (int r = 0; r < 4; ++r) {
            float v = rmin[rt][r];
            v = fminf(v, __shfl_xor(v, 1));
            v = fminf(v, __shfl_xor(v, 2));
            v = fminf(v, __shfl_xor(v, 4));
            v = fminf(v, __shfl_xor(v, 8));
            rmin[rt][r] = v;
        }

    if (lo == 0) {
        #pragma unroll
        for (int rt = 0; rt < 4; ++rt)
            #pragma unroll
            for (int r = 0; r < 4; ++r) {
                int row = row0 + rt * 16 + hi * 4 + r;
                float v = fmaxf(rmin[rt][r], 0.0f);   // distances >= 0
                atomicMin((int*)&minrow[row], __float_as_int(v));
            }
    }
}

// ---------------------------------------------------------------------------
// finalize: out = mean(minrow) + mean((m1-m2)^2) + mean(relu(0.1 - var1))
// ---------------------------------------------------------------------------
__global__ __launch_bounds__(256) void final_k(const unsigned* __restrict__ minrow,
                                               const float* __restrict__ colsum1,
                                               const float* __restrict__ colsum2,
                                               const float* __restrict__ colsumsq1,
                                               float* __restrict__ out) {
    __shared__ float red[256];
    const int tid = threadIdx.x;

    float s = 0.f;
    for (int i = tid; i < N_ROWS; i += 256)
        s += __int_as_float((int)minrow[i]);

    float m = 0.f;
    if (tid < DIMS) {
        const float inv_n = 1.0f / N_ROWS;
        float m1 = colsum1[tid] * inv_n;
        float m2 = colsum2[tid] * inv_n;
        float d  = m1 - m2;
        float var = colsumsq1[tid] * inv_n - m1 * m1;
        m = d * d + fmaxf(0.1f - var, 0.0f);
    }

    red[tid] = s * (1.0f / N_ROWS) + m * (1.0f / DIMS);
    __syncthreads();
    for (int off = 128; off; off >>= 1) {
        if (tid < off) red[tid] += red[tid + off];
        __syncthreads();
    }
    if (tid == 0) out[0] = red[0];
}

// ---------------------------------------------------------------------------
extern "C" void kernel_launch(void* const* d_in, const int* in_sizes, int n_in,
                              void* d_out, int out_size, void* d_ws, size_t ws_size,
                              hipStream_t stream) {
    (void)in_sizes; (void)n_in; (void)out_size; (void)ws_size;
    const float* c1 = (const float*)d_in[0];
    const float* c2 = (const float*)d_in[1];

    char* ws = (char*)d_ws;
    __hip_bfloat16* c1b = (__hip_bfloat16*)ws;                         // 2 MB
    __hip_bfloat16* c2b = (__hip_bfloat16*)(ws + (1u << 21));          // 2 MB
    float* sq1          = (float*)(ws + (1u << 22));                   // 32 KB
    float* sq2          = sq1 + N_ROWS;                                // 32 KB
    unsigned* minrow    = (unsigned*)(sq2 + N_ROWS);                   // 32 KB
    float* accum        = (float*)(minrow + N_ROWS);                   // 512 floats
    // accum: [0:128) colsum1, [128:256) colsum2, [256:384) colsumsq1,
    //        [384:512) colsumsq2 (computed, unused)

    init_k<<<32, 256, 0, stream>>>(minrow, accum);
    prep_k<<<64, 256, 0, stream>>>(c1, c1b, sq1, accum, accum + 256, -2.0f);
    prep_k<<<64, 256, 0, stream>>>(c2, c2b, sq2, accum + 128, accum + 384, 1.0f);
    dist_k<<<1024, 256, 0, stream>>>(c1b, c2b, sq1, sq2, minrow);
    final_k<<<1, 256, 0, stream>>>(minrow, accum, accum + 128, accum + 256, (float*)d_out);
}

// Round 2
// 59.238 us; speedup vs baseline: 1.6448x; 1.6448x over previous
//
#include <hip/hip_runtime.h>
#include <hip/hip_bf16.h>

#define N_ROWS 8192
#define DIMS   128

typedef __bf16 bf16x8 __attribute__((ext_vector_type(8)));
typedef float  f32x4  __attribute__((ext_vector_type(4)));

// Monotonic float <-> unsigned transform (handles negatives) for atomicMin.
__device__ __forceinline__ unsigned enc_f32(float f) {
    int i = __float_as_int(f);
    return (unsigned)(i ^ ((i >> 31) | 0x80000000));
}
__device__ __forceinline__ float dec_f32(unsigned u) {
    int i = (u & 0x80000000u) ? (int)(u ^ 0x80000000u) : ~(int)u;
    return __int_as_float(i);
}

// ---------------------------------------------------------------------------
// prep (fused): 128 blocks. blocks 0..63 -> cluster1 (scale -2 into bf16,
// row sq-norms, per-block partial colsum + colsumsq), blocks 64..127 ->
// cluster2 (scale +1, row sq-norms, partial colsum). Also inits minrow.
// part layout: [0:8192) colsum1 partials [64][128]
//              [8192:16384) colsumsq1 partials
//              [16384:24576) colsum2 partials
// ---------------------------------------------------------------------------
__global__ __launch_bounds__(256) void prep_k(const float* __restrict__ c1,
                                              const float* __restrict__ c2,
                                              __hip_bfloat16* __restrict__ c1b,
                                              __hip_bfloat16* __restrict__ c2b,
                                              float* __restrict__ sq1,
                                              float* __restrict__ sq2,
                                              float* __restrict__ part,
                                              unsigned* __restrict__ minrow) {
    const int tid  = threadIdx.x;
    const int lane = tid & 63;
    const int wave = tid >> 6;
    const int cl   = blockIdx.x >> 6;     // 0 = cluster1, 1 = cluster2
    const int blk  = blockIdx.x & 63;

    // init minrow (consumed by a LATER dispatch; any block may do it)
    if (tid < 64) minrow[blockIdx.x * 64 + tid] = 0xFFFFFFFFu;

    const float* __restrict__ src  = cl ? c2 : c1;
    __hip_bfloat16* __restrict__ dst = cl ? c2b : c1b;
    float* __restrict__ sq         = cl ? sq2 : sq1;
    const float scale              = cl ? 1.0f : -2.0f;

    float cs0 = 0.f, cs1 = 0.f, cq0 = 0.f, cq1 = 0.f;
    const int gw = blk * 4 + wave;        // 0..255 within this cluster

    for (int i = 0; i < 32; ++i) {
        const int row = gw + i * 256;
        float x0 = src[row * DIMS + lane];
        float x1 = src[row * DIMS + 64 + lane];
        dst[row * DIMS + lane]      = __float2bfloat16(scale * x0);
        dst[row * DIMS + 64 + lane] = __float2bfloat16(scale * x1);
        float s = x0 * x0 + x1 * x1;
        #pragma unroll
        for (int m = 32; m; m >>= 1) s += __shfl_xor(s, m);
        if (lane == 0) sq[row] = s;
        cs0 += x0; cs1 += x1;
        cq0 += x0 * x0; cq1 += x1 * x1;
    }

    __shared__ float lds[4][DIMS];
    lds[wave][lane]      = cs0;
    lds[wave][64 + lane] = cs1;
    __syncthreads();
    if (tid < DIMS) {
        float t = lds[0][tid] + lds[1][tid] + lds[2][tid] + lds[3][tid];
        if (cl == 0) part[blk * DIMS + tid] = t;
        else         part[16384 + blk * DIMS + tid] = t;
    }
    __syncthreads();
    lds[wave][lane]      = cq0;
    lds[wave][64 + lane] = cq1;
    __syncthreads();
    if (tid < DIMS && cl == 0) {
        float t = lds[0][tid] + lds[1][tid] + lds[2][tid] + lds[3][tid];
        part[8192 + blk * DIMS + tid] = t;
    }
}

// ---------------------------------------------------------------------------
// dist: grid 16 row-blocks x 32 col-chunks. Block = 512 rows x 256 cols.
// Wave owns 128 rows; A frags (c1b pre-scaled by -2) resident in registers
// (a[8][4] = 128 VGPRs; __launch_bounds__(256,2) gives the 256-VGPR budget).
// Accumulator C-in = sq2[J] so the MFMA chain yields sq2 - 2*c1.c2 directly;
// epilogue is a single fmin per element. sq1 is added in final_k.
// MFMA 16x16x32 bf16 layouts (validated round 1, absmax 0.0):
//   A: row = lane&15, k = (lane>>4)*8 + j
//   B: col = lane&15, k = (lane>>4)*8 + j   (B[k][n] = c2[n][k])
//   D: col = lane&15, row = (lane>>4)*4 + r
// ---------------------------------------------------------------------------
__global__ __launch_bounds__(256, 2) void dist_k(const __hip_bfloat16* __restrict__ c1b,
                                                 const __hip_bfloat16* __restrict__ c2b,
                                                 const float* __restrict__ sq2,
                                                 unsigned* __restrict__ minrow) {
    const int lane = threadIdx.x & 63;
    const int wave = threadIdx.x >> 6;
    const int lo = lane & 15;
    const int hi = lane >> 4;
    const int rb = blockIdx.x >> 5;     // 0..15 : 512-row block
    const int cb = blockIdx.x & 31;     // 0..31 : 256-col chunk
    const int row0 = rb * 512 + wave * 128;
    const int col0 = cb * 256;

    // A fragments: 8 row-subtiles x 4 k-steps, resident.
    bf16x8 a[8][4];
    #pragma unroll
    for (int rt = 0; rt < 8; ++rt)
        #pragma unroll
        for (int ks = 0; ks < 4; ++ks)
            a[rt][ks] = *reinterpret_cast<const bf16x8*>(
                c1b + (size_t)(row0 + rt * 16 + lo) * DIMS + ks * 32 + hi * 8);

    float rmin[8][4];
    #pragma unroll
    for (int rt = 0; rt < 8; ++rt)
        #pragma unroll
        for (int r = 0; r < 4; ++r)
            rmin[rt][r] = __builtin_inff();

    #pragma unroll 2
    for (int ct = 0; ct < 16; ++ct) {
        const int J = col0 + ct * 16 + lo;
        const float t = sq2[J];
        bf16x8 b[4];
        #pragma unroll
        for (int ks = 0; ks < 4; ++ks)
            b[ks] = *reinterpret_cast<const bf16x8*>(
                c2b + (size_t)J * DIMS + ks * 32 + hi * 8);

        #pragma unroll
        for (int rt = 0; rt < 8; ++rt) {
            f32x4 acc = {t, t, t, t};          // C-in = sq2[col]
            #pragma unroll
            for (int ks = 0; ks < 4; ++ks)
                acc = __builtin_amdgcn_mfma_f32_16x16x32_bf16(a[rt][ks], b[ks], acc, 0, 0, 0);
            #pragma unroll
            for (int r = 0; r < 4; ++r)
                rmin[rt][r] = fminf(rmin[rt][r], acc[r]);  // sq2 - 2*c1.c2
        }
    }

    // min across the 16 lanes sharing an output row
    #pragma unroll
    for (int rt = 0; rt < 8; ++rt)
        #pragma unroll
        for (int r = 0; r < 4; ++r) {
            float v = rmin[rt][r];
            v = fminf(v, __shfl_xor(v, 1));
            v = fminf(v, __shfl_xor(v, 2));
            v = fminf(v, __shfl_xor(v, 4));
            v = fminf(v, __shfl_xor(v, 8));
            rmin[rt][r] = v;
        }

    if (lo == 0) {
        #pragma unroll
        for (int rt = 0; rt < 8; ++rt)
            #pragma unroll
            for (int r = 0; r < 4; ++r) {
                int row = row0 + rt * 16 + hi * 4 + r;
                atomicMin(&minrow[row], enc_f32(rmin[rt][r]));
            }
    }
}

// ---------------------------------------------------------------------------
// finalize: out = mean_i(dec(minrow[i]) + sq1[i])
//               + mean_c((m1-m2)^2) + mean_c(relu(0.1 - var1))
// ---------------------------------------------------------------------------
__global__ __launch_bounds__(256) void final_k(const unsigned* __restrict__ minrow,
                                               const float* __restrict__ sq1,
                                               const float* __restrict__ part,
                                               float* __restrict__ out) {
    __shared__ float red[256];
    const int tid = threadIdx.x;

    float s = 0.f;
    for (int i = tid; i < N_ROWS; i += 256)
        s += dec_f32(minrow[i]) + sq1[i];

    float m = 0.f;
    if (tid < DIMS) {
        float cs1 = 0.f, cq1 = 0.f, cs2 = 0.f;
        for (int b = 0; b < 64; ++b) {
            cs1 += part[b * DIMS + tid];
            cq1 += part[8192 + b * DIMS + tid];
            cs2 += part[16384 + b * DIMS + tid];
        }
        const float inv_n = 1.0f / N_ROWS;
        float m1 = cs1 * inv_n;
        float m2 = cs2 * inv_n;
        float d  = m1 - m2;
        float var = cq1 * inv_n - m1 * m1;
        m = d * d + fmaxf(0.1f - var, 0.0f);
    }

    red[tid] = s * (1.0f / N_ROWS) + m * (1.0f / DIMS);
    __syncthreads();
    for (int off = 128; off; off >>= 1) {
        if (tid < off) red[tid] += red[tid + off];
        __syncthreads();
    }
    if (tid == 0) out[0] = red[0];
}

// ---------------------------------------------------------------------------
extern "C" void kernel_launch(void* const* d_in, const int* in_sizes, int n_in,
                              void* d_out, int out_size, void* d_ws, size_t ws_size,
                              hipStream_t stream) {
    (void)in_sizes; (void)n_in; (void)out_size; (void)ws_size;
    const float* c1 = (const float*)d_in[0];
    const float* c2 = (const float*)d_in[1];

    char* ws = (char*)d_ws;
    __hip_bfloat16* c1b = (__hip_bfloat16*)ws;                    // 2 MB
    __hip_bfloat16* c2b = (__hip_bfloat16*)(ws + (1u << 21));     // 2 MB
    float* sq1          = (float*)(ws + (1u << 22));              // 32 KB
    float* sq2          = sq1 + N_ROWS;                           // 32 KB
    unsigned* minrow    = (unsigned*)(sq2 + N_ROWS);              // 32 KB
    float* part         = (float*)(minrow + N_ROWS);              // 96 KB

    prep_k<<<128, 256, 0, stream>>>(c1, c2, c1b, c2b, sq1, sq2, part, minrow);
    dist_k<<<512, 256, 0, stream>>>(c1b, c2b, sq2, minrow);
    final_k<<<1, 256, 0, stream>>>(minrow, sq1, part, (float*)d_out);
}

// Round 3
// 52.775 us; speedup vs baseline: 1.8462x; 1.1225x over previous
//
#include <hip/hip_runtime.h>
#include <hip/hip_bf16.h>

#define N_ROWS 8192
#define DIMS   128

typedef __bf16 bf16x8 __attribute__((ext_vector_type(8)));
typedef float  f32x4  __attribute__((ext_vector_type(4)));

// Monotonic float <-> unsigned transform (handles negatives) for atomicMin.
__device__ __forceinline__ unsigned enc_f32(float f) {
    int i = __float_as_int(f);
    return (unsigned)(i ^ ((i >> 31) | 0x80000000));
}
__device__ __forceinline__ float dec_f32(unsigned u) {
    int i = (u & 0x80000000u) ? (int)(u ^ 0x80000000u) : ~(int)u;
    return __int_as_float(i);
}

struct alignas(8) B4 { __hip_bfloat16 h0, h1, h2, h3; };

// ---------------------------------------------------------------------------
// prep: 256 blocks; blocks 0..127 -> cluster1 (bf16 copy scaled by -2, row
// sq-norms, per-block partial colsum + colsumsq), 128..255 -> cluster2
// (scale +1, partial colsum). float4 loads, 2 rows per wave-iteration
// (lanes 0-31 = even row, 32-63 = odd row). Also inits minrow.
// part layout: [0:16384) colsum1 partials [128][128]
//              [16384:32768) colsumsq1 partials
//              [32768:49152) colsum2 partials
// ---------------------------------------------------------------------------
__global__ __launch_bounds__(256) void prep_k(const float* __restrict__ c1,
                                              const float* __restrict__ c2,
                                              __hip_bfloat16* __restrict__ c1b,
                                              __hip_bfloat16* __restrict__ c2b,
                                              float* __restrict__ sq1,
                                              float* __restrict__ sq2,
                                              float* __restrict__ part,
                                              unsigned* __restrict__ minrow) {
    const int tid  = threadIdx.x;
    const int lane = tid & 63;
    const int wave = tid >> 6;
    const int half = lane >> 5;           // 0: even row, 1: odd row
    const int l32  = lane & 31;           // cols 4*l32 .. 4*l32+3
    const int cl   = blockIdx.x >> 7;     // 0 = cluster1, 1 = cluster2
    const int blk  = blockIdx.x & 127;

    if (tid < 32) minrow[blockIdx.x * 32 + tid] = 0xFFFFFFFFu;

    const float* __restrict__ src    = cl ? c2 : c1;
    __hip_bfloat16* __restrict__ dst = cl ? c2b : c1b;
    float* __restrict__ sq           = cl ? sq2 : sq1;
    const float scale                = cl ? 1.0f : -2.0f;

    float4 cs = {0.f, 0.f, 0.f, 0.f};
    float4 cq = {0.f, 0.f, 0.f, 0.f};

    #pragma unroll 4
    for (int i = 0; i < 8; ++i) {
        const int row = blk * 64 + wave * 16 + i * 2 + half;
        float4 x = *reinterpret_cast<const float4*>(src + (size_t)row * DIMS + l32 * 4);
        B4 b4{__float2bfloat16(scale * x.x), __float2bfloat16(scale * x.y),
              __float2bfloat16(scale * x.z), __float2bfloat16(scale * x.w)};
        *reinterpret_cast<B4*>(dst + (size_t)row * DIMS + l32 * 4) = b4;
        float s = x.x * x.x + x.y * x.y + x.z * x.z + x.w * x.w;
        #pragma unroll
        for (int m = 16; m; m >>= 1) s += __shfl_xor(s, m);   // within 32-lane half
        if (l32 == 0) sq[row] = s;
        cs.x += x.x; cs.y += x.y; cs.z += x.z; cs.w += x.w;
        cq.x += x.x * x.x; cq.y += x.y * x.y; cq.z += x.z * x.z; cq.w += x.w * x.w;
    }

    // combine halves (same columns in both halves)
    cs.x += __shfl_xor(cs.x, 32); cs.y += __shfl_xor(cs.y, 32);
    cs.z += __shfl_xor(cs.z, 32); cs.w += __shfl_xor(cs.w, 32);
    cq.x += __shfl_xor(cq.x, 32); cq.y += __shfl_xor(cq.y, 32);
    cq.z += __shfl_xor(cq.z, 32); cq.w += __shfl_xor(cq.w, 32);

    __shared__ float4 lds4[4][32];
    lds4[wave][l32] = cs;
    __syncthreads();
    if (tid < 32) {
        float4 a = lds4[0][tid], b = lds4[1][tid], c = lds4[2][tid], d = lds4[3][tid];
        float4 t = {a.x + b.x + c.x + d.x, a.y + b.y + c.y + d.y,
                    a.z + b.z + c.z + d.z, a.w + b.w + c.w + d.w};
        float* p = part + (cl ? 32768 : 0) + blk * DIMS + tid * 4;
        *reinterpret_cast<float4*>(p) = t;
    }
    __syncthreads();
    lds4[wave][l32] = cq;
    __syncthreads();
    if (tid < 32 && cl == 0) {
        float4 a = lds4[0][tid], b = lds4[1][tid], c = lds4[2][tid], d = lds4[3][tid];
        float4 t = {a.x + b.x + c.x + d.x, a.y + b.y + c.y + d.y,
                    a.z + b.z + c.z + d.z, a.w + b.w + c.w + d.w};
        *reinterpret_cast<float4*>(part + 16384 + blk * DIMS + tid * 4) = t;
    }
}

// ---------------------------------------------------------------------------
// dist: grid 16 row-blocks x 32 col-chunks. Wave owns 128 rows; A frags
// (c1b pre-scaled by -2) resident (a[8][4] = 128 VGPRs). B fragments
// software-pipelined: prefetch ct+1 before the MFMA cluster of ct.
// C-in = sq2[col] so the chain yields sq2 - 2*c1.c2; epilogue = fmin.
// MFMA 16x16x32 bf16 layouts (validated: absmax 0.0):
//   A: row = lane&15, k = (lane>>4)*8 + j
//   B: col = lane&15, k = (lane>>4)*8 + j
//   D: col = lane&15, row = (lane>>4)*4 + r
// ---------------------------------------------------------------------------
__global__ __launch_bounds__(256, 2) void dist_k(const __hip_bfloat16* __restrict__ c1b,
                                                 const __hip_bfloat16* __restrict__ c2b,
                                                 const float* __restrict__ sq2,
                                                 unsigned* __restrict__ minrow) {
    const int lane = threadIdx.x & 63;
    const int wave = threadIdx.x >> 6;
    const int lo = lane & 15;
    const int hi = lane >> 4;
    const int rb = blockIdx.x >> 5;     // 0..15 : 512-row block
    const int cb = blockIdx.x & 31;     // 0..31 : 256-col chunk
    const int row0 = rb * 512 + wave * 128;
    const int col0 = cb * 256;

    // A fragments: 8 row-subtiles x 4 k-steps, register-resident.
    bf16x8 a[8][4];
    #pragma unroll
    for (int rt = 0; rt < 8; ++rt)
        #pragma unroll
        for (int ks = 0; ks < 4; ++ks)
            a[rt][ks] = *reinterpret_cast<const bf16x8*>(
                c1b + (size_t)(row0 + rt * 16 + lo) * DIMS + ks * 32 + hi * 8);

    float rmin[8][4];
    #pragma unroll
    for (int rt = 0; rt < 8; ++rt)
        #pragma unroll
        for (int r = 0; r < 4; ++r)
            rmin[rt][r] = __builtin_inff();

    // prologue: prefetch ct = 0
    bf16x8 bcur[4];
    float tcur;
    {
        const int J = col0 + lo;
        tcur = sq2[J];
        #pragma unroll
        for (int ks = 0; ks < 4; ++ks)
            bcur[ks] = *reinterpret_cast<const bf16x8*>(
                c2b + (size_t)J * DIMS + ks * 32 + hi * 8);
    }

    #pragma unroll 2
    for (int ct = 0; ct < 16; ++ct) {
        // prefetch ct+1 (wrap-around on the last iteration: valid addr, unused)
        const int Jn = col0 + (((ct + 1) & 15) << 4) + lo;
        const float tnext = sq2[Jn];
        bf16x8 bnext[4];
        #pragma unroll
        for (int ks = 0; ks < 4; ++ks)
            bnext[ks] = *reinterpret_cast<const bf16x8*>(
                c2b + (size_t)Jn * DIMS + ks * 32 + hi * 8);

        __builtin_amdgcn_s_setprio(1);
        #pragma unroll
        for (int rt = 0; rt < 8; ++rt) {
            f32x4 acc = {tcur, tcur, tcur, tcur};     // C-in = sq2[col]
            #pragma unroll
            for (int ks = 0; ks < 4; ++ks)
                acc = __builtin_amdgcn_mfma_f32_16x16x32_bf16(a[rt][ks], bcur[ks], acc, 0, 0, 0);
            #pragma unroll
            for (int r = 0; r < 4; ++r)
                rmin[rt][r] = fminf(rmin[rt][r], acc[r]);
        }
        __builtin_amdgcn_s_setprio(0);

        #pragma unroll
        for (int ks = 0; ks < 4; ++ks) bcur[ks] = bnext[ks];
        tcur = tnext;
    }

    // min across the 16 lanes sharing an output row
    #pragma unroll
    for (int rt = 0; rt < 8; ++rt)
        #pragma unroll
        for (int r = 0; r < 4; ++r) {
            float v = rmin[rt][r];
            v = fminf(v, __shfl_xor(v, 1));
            v = fminf(v, __shfl_xor(v, 2));
            v = fminf(v, __shfl_xor(v, 4));
            v = fminf(v, __shfl_xor(v, 8));
            rmin[rt][r] = v;
        }

    if (lo == 0) {
        #pragma unroll
        for (int rt = 0; rt < 8; ++rt)
            #pragma unroll
            for (int r = 0; r < 4; ++r) {
                int row = row0 + rt * 16 + hi * 4 + r;
                atomicMin(&minrow[row], enc_f32(rmin[rt][r]));
            }
    }
}

// ---------------------------------------------------------------------------
// finalize: out = mean_i(dec(minrow[i]) + sq1[i])
//               + mean_c((m1-m2)^2) + mean_c(relu(0.1 - var1))
// ---------------------------------------------------------------------------
__global__ __launch_bounds__(256) void final_k(const unsigned* __restrict__ minrow,
                                               const float* __restrict__ sq1,
                                               const float* __restrict__ part,
                                               float* __restrict__ out) {
    __shared__ float red[256];
    const int tid = threadIdx.x;

    const uint4*  m4 = reinterpret_cast<const uint4*>(minrow);
    const float4* q4 = reinterpret_cast<const float4*>(sq1);
    float s = 0.f;
    #pragma unroll 2
    for (int i = tid; i < N_ROWS / 4; i += 256) {
        uint4  u = m4[i];
        float4 q = q4[i];
        s += dec_f32(u.x) + dec_f32(u.y) + dec_f32(u.z) + dec_f32(u.w)
           + q.x + q.y + q.z + q.w;
    }

    float m = 0.f;
    if (tid < DIMS) {
        float cs1 = 0.f, cq1 = 0.f, cs2 = 0.f;
        #pragma unroll 4
        for (int b = 0; b < 128; ++b) {
            cs1 += part[b * DIMS + tid];
            cq1 += part[16384 + b * DIMS + tid];
            cs2 += part[32768 + b * DIMS + tid];
        }
        const float inv_n = 1.0f / N_ROWS;
        float m1 = cs1 * inv_n;
        float m2 = cs2 * inv_n;
        float d  = m1 - m2;
        float var = cq1 * inv_n - m1 * m1;
        m = d * d + fmaxf(0.1f - var, 0.0f);
    }

    red[tid] = s * (1.0f / N_ROWS) + m * (1.0f / DIMS);
    __syncthreads();
    for (int off = 128; off; off >>= 1) {
        if (tid < off) red[tid] += red[tid + off];
        __syncthreads();
    }
    if (tid == 0) out[0] = red[0];
}

// ---------------------------------------------------------------------------
extern "C" void kernel_launch(void* const* d_in, const int* in_sizes, int n_in,
                              void* d_out, int out_size, void* d_ws, size_t ws_size,
                              hipStream_t stream) {
    (void)in_sizes; (void)n_in; (void)out_size; (void)ws_size;
    const float* c1 = (const float*)d_in[0];
    const float* c2 = (const float*)d_in[1];

    char* ws = (char*)d_ws;
    __hip_bfloat16* c1b = (__hip_bfloat16*)ws;                    // 2 MB
    __hip_bfloat16* c2b = (__hip_bfloat16*)(ws + (1u << 21));     // 2 MB
    float* sq1          = (float*)(ws + (1u << 22));              // 32 KB
    float* sq2          = sq1 + N_ROWS;                           // 32 KB
    unsigned* minrow    = (unsigned*)(sq2 + N_ROWS);              // 32 KB
    float* part         = (float*)(minrow + N_ROWS);              // 192 KB

    prep_k<<<256, 256, 0, stream>>>(c1, c2, c1b, c2b, sq1, sq2, part, minrow);
    dist_k<<<512, 256, 0, stream>>>(c1b, c2b, sq2, minrow);
    final_k<<<1, 256, 0, stream>>>(minrow, sq1, part, (float*)d_out);
}

// Round 4
// 51.609 us; speedup vs baseline: 1.8879x; 1.0226x over previous
//
#include <hip/hip_runtime.h>
#include <hip/hip_bf16.h>

#define N_ROWS 8192
#define DIMS   128

typedef __bf16 bf16x8 __attribute__((ext_vector_type(8)));
typedef float  f32x4  __attribute__((ext_vector_type(4)));

// Monotonic float <-> unsigned transform (handles negatives) for atomicMin.
__device__ __forceinline__ unsigned enc_f32(float f) {
    int i = __float_as_int(f);
    return (unsigned)(i ^ ((i >> 31) | 0x80000000));
}
__device__ __forceinline__ float dec_f32(unsigned u) {
    int i = (u & 0x80000000u) ? (int)(u ^ 0x80000000u) : ~(int)u;
    return __int_as_float(i);
}

struct alignas(8) B4 { __hip_bfloat16 h0, h1, h2, h3; };

// ---------------------------------------------------------------------------
// prep: 256 blocks; blocks 0..127 -> cluster1 (bf16 copy scaled by -2, row
// sq-norms, per-block partial colsum + colsumsq), 128..255 -> cluster2
// (scale +1, partial colsum). float4 loads, 2 rows per wave-iteration.
// part layout (TRANSPOSED for coalesced final reads):
//   part[sec*16384 + col*128 + blk], sec 0=colsum1, 1=colsumsq1, 2=colsum2
// ---------------------------------------------------------------------------
__global__ __launch_bounds__(256) void prep_k(const float* __restrict__ c1,
                                              const float* __restrict__ c2,
                                              __hip_bfloat16* __restrict__ c1b,
                                              __hip_bfloat16* __restrict__ c2b,
                                              float* __restrict__ sq1,
                                              float* __restrict__ sq2,
                                              float* __restrict__ part,
                                              unsigned* __restrict__ minrow) {
    const int tid  = threadIdx.x;
    const int lane = tid & 63;
    const int wave = tid >> 6;
    const int half = lane >> 5;           // 0: even row, 1: odd row
    const int l32  = lane & 31;           // cols 4*l32 .. 4*l32+3
    const int cl   = blockIdx.x >> 7;     // 0 = cluster1, 1 = cluster2
    const int blk  = blockIdx.x & 127;

    if (tid < 32) minrow[blockIdx.x * 32 + tid] = 0xFFFFFFFFu;

    const float* __restrict__ src    = cl ? c2 : c1;
    __hip_bfloat16* __restrict__ dst = cl ? c2b : c1b;
    float* __restrict__ sq           = cl ? sq2 : sq1;
    const float scale                = cl ? 1.0f : -2.0f;

    float4 cs = {0.f, 0.f, 0.f, 0.f};
    float4 cq = {0.f, 0.f, 0.f, 0.f};

    #pragma unroll 4
    for (int i = 0; i < 8; ++i) {
        const int row = blk * 64 + wave * 16 + i * 2 + half;
        float4 x = *reinterpret_cast<const float4*>(src + (size_t)row * DIMS + l32 * 4);
        B4 b4{__float2bfloat16(scale * x.x), __float2bfloat16(scale * x.y),
              __float2bfloat16(scale * x.z), __float2bfloat16(scale * x.w)};
        *reinterpret_cast<B4*>(dst + (size_t)row * DIMS + l32 * 4) = b4;
        float s = x.x * x.x + x.y * x.y + x.z * x.z + x.w * x.w;
        #pragma unroll
        for (int m = 16; m; m >>= 1) s += __shfl_xor(s, m);   // within 32-lane half
        if (l32 == 0) sq[row] = s;
        cs.x += x.x; cs.y += x.y; cs.z += x.z; cs.w += x.w;
        cq.x += x.x * x.x; cq.y += x.y * x.y; cq.z += x.z * x.z; cq.w += x.w * x.w;
    }

    // combine halves (same columns in both halves)
    cs.x += __shfl_xor(cs.x, 32); cs.y += __shfl_xor(cs.y, 32);
    cs.z += __shfl_xor(cs.z, 32); cs.w += __shfl_xor(cs.w, 32);
    cq.x += __shfl_xor(cq.x, 32); cq.y += __shfl_xor(cq.y, 32);
    cq.z += __shfl_xor(cq.z, 32); cq.w += __shfl_xor(cq.w, 32);

    __shared__ float4 lds4[4][32];
    lds4[wave][l32] = cs;
    __syncthreads();
    if (tid < 32) {
        float4 a = lds4[0][tid], b = lds4[1][tid], c = lds4[2][tid], d = lds4[3][tid];
        float4 t = {a.x + b.x + c.x + d.x, a.y + b.y + c.y + d.y,
                    a.z + b.z + c.z + d.z, a.w + b.w + c.w + d.w};
        const int base = cl ? 32768 : 0;
        part[base + (4 * tid + 0) * 128 + blk] = t.x;
        part[base + (4 * tid + 1) * 128 + blk] = t.y;
        part[base + (4 * tid + 2) * 128 + blk] = t.z;
        part[base + (4 * tid + 3) * 128 + blk] = t.w;
    }
    __syncthreads();
    lds4[wave][l32] = cq;
    __syncthreads();
    if (tid < 32 && cl == 0) {
        float4 a = lds4[0][tid], b = lds4[1][tid], c = lds4[2][tid], d = lds4[3][tid];
        float4 t = {a.x + b.x + c.x + d.x, a.y + b.y + c.y + d.y,
                    a.z + b.z + c.z + d.z, a.w + b.w + c.w + d.w};
        part[16384 + (4 * tid + 0) * 128 + blk] = t.x;
        part[16384 + (4 * tid + 1) * 128 + blk] = t.y;
        part[16384 + (4 * tid + 2) * 128 + blk] = t.z;
        part[16384 + (4 * tid + 3) * 128 + blk] = t.w;
    }
}

// ---------------------------------------------------------------------------
// dist: grid 16 row-blocks x 32 col-chunks. Wave owns 128 rows. A fragments
// loaded as uint4 and passed through an opaque asm fence -> the compiler
// CANNOT rematerialize the loads inside the ct loop; they stay in 128 VGPRs.
// B fragments software-pipelined (prefetch ct+1). C-in = sq2[col] so the
// MFMA chain yields sq2 - 2*c1.c2; epilogue = fmin. sq1 added at atomicMin.
// MFMA 16x16x32 bf16 layouts (validated: absmax 0.0):
//   A: row = lane&15, k = (lane>>4)*8 + j
//   B: col = lane&15, k = (lane>>4)*8 + j
//   D: col = lane&15, row = (lane>>4)*4 + r
// ---------------------------------------------------------------------------
__global__ __launch_bounds__(256, 2) void dist_k(const __hip_bfloat16* __restrict__ c1b,
                                                 const __hip_bfloat16* __restrict__ c2b,
                                                 const float* __restrict__ sq1,
                                                 const float* __restrict__ sq2,
                                                 unsigned* __restrict__ minrow) {
    const int lane = threadIdx.x & 63;
    const int wave = threadIdx.x >> 6;
    const int lo = lane & 15;
    const int hi = lane >> 4;
    const int rb = blockIdx.x >> 5;     // 0..15 : 512-row block
    const int cb = blockIdx.x & 31;     // 0..31 : 256-col chunk
    const int row0 = rb * 512 + wave * 128;
    const int col0 = cb * 256;

    // A fragments: 8 row-subtiles x 4 k-steps, register-resident (forced).
    uint4 a_u[8][4];
    #pragma unroll
    for (int rt = 0; rt < 8; ++rt)
        #pragma unroll
        for (int ks = 0; ks < 4; ++ks)
            a_u[rt][ks] = *reinterpret_cast<const uint4*>(
                c1b + (size_t)(row0 + rt * 16 + lo) * DIMS + ks * 32 + hi * 8);

    // Opaque fence: values become asm outputs -> no rematerialization.
    #pragma unroll
    for (int rt = 0; rt < 8; ++rt)
        #pragma unroll
        for (int ks = 0; ks < 4; ++ks)
            asm volatile("" : "+v"(a_u[rt][ks].x), "+v"(a_u[rt][ks].y),
                              "+v"(a_u[rt][ks].z), "+v"(a_u[rt][ks].w));

    float rmin[8][4];
    #pragma unroll
    for (int rt = 0; rt < 8; ++rt)
        #pragma unroll
        for (int r = 0; r < 4; ++r)
            rmin[rt][r] = __builtin_inff();

    // prologue: prefetch ct = 0
    bf16x8 bcur[4];
    float tcur;
    {
        const int J = col0 + lo;
        tcur = sq2[J];
        #pragma unroll
        for (int ks = 0; ks < 4; ++ks)
            bcur[ks] = *reinterpret_cast<const bf16x8*>(
                c2b + (size_t)J * DIMS + ks * 32 + hi * 8);
    }

    #pragma unroll 2
    for (int ct = 0; ct < 16; ++ct) {
        // prefetch ct+1 (wrap-around on the last iteration: valid addr, unused)
        const int Jn = col0 + (((ct + 1) & 15) << 4) + lo;
        const float tnext = sq2[Jn];
        bf16x8 bnext[4];
        #pragma unroll
        for (int ks = 0; ks < 4; ++ks)
            bnext[ks] = *reinterpret_cast<const bf16x8*>(
                c2b + (size_t)Jn * DIMS + ks * 32 + hi * 8);

        __builtin_amdgcn_s_setprio(1);
        #pragma unroll
        for (int rt = 0; rt < 8; ++rt) {
            f32x4 acc = {tcur, tcur, tcur, tcur};     // C-in = sq2[col]
            #pragma unroll
            for (int ks = 0; ks < 4; ++ks)
                acc = __builtin_amdgcn_mfma_f32_16x16x32_bf16(
                    __builtin_bit_cast(bf16x8, a_u[rt][ks]), bcur[ks], acc, 0, 0, 0);
            #pragma unroll
            for (int r = 0; r < 4; ++r)
                rmin[rt][r] = fminf(rmin[rt][r], acc[r]);
        }
        __builtin_amdgcn_s_setprio(0);

        #pragma unroll
        for (int ks = 0; ks < 4; ++ks) bcur[ks] = bnext[ks];
        tcur = tnext;
    }

    // min across the 16 lanes sharing an output row
    #pragma unroll
    for (int rt = 0; rt < 8; ++rt)
        #pragma unroll
        for (int r = 0; r < 4; ++r) {
            float v = rmin[rt][r];
            v = fminf(v, __shfl_xor(v, 1));
            v = fminf(v, __shfl_xor(v, 2));
            v = fminf(v, __shfl_xor(v, 4));
            v = fminf(v, __shfl_xor(v, 8));
            rmin[rt][r] = v;
        }

    if (lo == 0) {
        #pragma unroll
        for (int rt = 0; rt < 8; ++rt)
            #pragma unroll
            for (int r = 0; r < 4; ++r) {
                int row = row0 + rt * 16 + hi * 4 + r;
                atomicMin(&minrow[row], enc_f32(rmin[rt][r] + sq1[row]));
            }
    }
}

// ---------------------------------------------------------------------------
// finalize: out = mean_i(dec(minrow[i]))            [sq1 already folded in]
//               + mean_c((m1-m2)^2) + mean_c(relu(0.1 - var1))
// part[sec][col][blk]: each col-stat job reads 128 consecutive floats.
// ---------------------------------------------------------------------------
__global__ __launch_bounds__(256) void final_k(const unsigned* __restrict__ minrow,
                                               const float* __restrict__ part,
                                               float* __restrict__ out) {
    __shared__ float red[256];
    __shared__ float cs[384];
    const int tid = threadIdx.x;

    // column-stat jobs: j = sec*128 + col, each sums part[j*128 .. j*128+128)
    for (int j = tid; j < 384; j += 256) {
        const float4* p = reinterpret_cast<const float4*>(part + j * 128);
        float4 a = {0.f, 0.f, 0.f, 0.f};
        #pragma unroll 8
        for (int b = 0; b < 32; ++b) {
            float4 v = p[b];
            a.x += v.x; a.y += v.y; a.z += v.z; a.w += v.w;
        }
        cs[j] = a.x + a.y + a.z + a.w;
    }

    const uint4* m4 = reinterpret_cast<const uint4*>(minrow);
    float s = 0.f;
    #pragma unroll 2
    for (int i = tid; i < N_ROWS / 4; i += 256) {
        uint4 u = m4[i];
        s += dec_f32(u.x) + dec_f32(u.y) + dec_f32(u.z) + dec_f32(u.w);
    }

    __syncthreads();
    float m = 0.f;
    if (tid < DIMS) {
        const float inv_n = 1.0f / N_ROWS;
        float m1 = cs[tid] * inv_n;
        float vq = cs[128 + tid] * inv_n;
        float m2 = cs[256 + tid] * inv_n;
        float d  = m1 - m2;
        float var = vq - m1 * m1;
        m = d * d + fmaxf(0.1f - var, 0.0f);
    }

    red[tid] = s * (1.0f / N_ROWS) + m * (1.0f / DIMS);
    __syncthreads();
    for (int off = 128; off; off >>= 1) {
        if (tid < off) red[tid] += red[tid + off];
        __syncthreads();
    }
    if (tid == 0) out[0] = red[0];
}

// ---------------------------------------------------------------------------
extern "C" void kernel_launch(void* const* d_in, const int* in_sizes, int n_in,
                              void* d_out, int out_size, void* d_ws, size_t ws_size,
                              hipStream_t stream) {
    (void)in_sizes; (void)n_in; (void)out_size; (void)ws_size;
    const float* c1 = (const float*)d_in[0];
    const float* c2 = (const float*)d_in[1];

    char* ws = (char*)d_ws;
    __hip_bfloat16* c1b = (__hip_bfloat16*)ws;                    // 2 MB
    __hip_bfloat16* c2b = (__hip_bfloat16*)(ws + (1u << 21));     // 2 MB
    float* sq1          = (float*)(ws + (1u << 22));              // 32 KB
    float* sq2          = sq1 + N_ROWS;                           // 32 KB
    unsigned* minrow    = (unsigned*)(sq2 + N_ROWS);              // 32 KB
    float* part         = (float*)(minrow + N_ROWS);              // 192 KB

    prep_k<<<256, 256, 0, stream>>>(c1, c2, c1b, c2b, sq1, sq2, part, minrow);
    dist_k<<<512, 256, 0, stream>>>(c1b, c2b, sq1, sq2, minrow);
    final_k<<<1, 256, 0, stream>>>(minrow, part, (float*)d_out);
}